// Round 8
// baseline (439.119 us; speedup 1.0000x reference)
//
#include <hip/hip_runtime.h>
#include <cstdint>

#define NB 64
#define NC 256
#define ND 256
#define NT 4096

#define BT 32                    // t-columns per tile
#define NTILES 8                 // tiles per block
#define CHUNK (BT * NTILES)      // 256 t per block
#define NCHUNK (NT / CHUNK)      // 16 chunks -> 1024 blocks = 4 per CU

typedef __attribute__((ext_vector_type(8)))  _Float16 half8;
typedef __attribute__((ext_vector_type(16))) float    f32x16;

union FragA { uint32_t u[4]; uint4 q; half8 v; };

__device__ __forceinline__ uint32_t pk_f16(float lo, float hi) {
    // v_cvt_pkrtz_f16_f32: D.lo=f16(lo), D.hi=f16(hi) — matches MFMA (k even, k odd) packing
    return __builtin_bit_cast(uint32_t, __builtin_amdgcn_cvt_pkrtz(lo, hi));
}

// Structure: 512-thread blocks (8 waves), each wave owns d in [wv*32, wv*32+32),
// block covers full d=0..255 for a 256-t chunk in 8 tiles of BT=32.
// 4 blocks/CU (32 KiB LDS each, VGPR=64 -> 8 waves/SIMD): four independent
// barrier groups per CU — while one drains at __syncthreads, three stream.
// (R7 measured 2 blocks/CU at 126 µs with VGPR=64; resources allow 4, grid
//  was the only limiter. Do NOT tighten launch_bounds below (512,4): R3
//  showed forcing the allocator below its natural ~64-100 regs spills.)
//
// Sync: plain __syncthreads() — R6's lgkm-only barrier raced under replay.
//
// LDS (per buffer, 16 KiB): fp16 x-tile [t=0..31][c=0..255], row = 512 B,
// byte(t,c) = t*512 + ((2c) ^ ((t&15)<<4))  — XOR swizzle, same on write & read.
//
// MFMA: D[m=d][n=t] = sum_c W^T[d][c] * X[c][t]
//   A = W frag (lane&31 = d, k = 8*(lane>>5)+j), B = x frag (lane&31 = t)
//   C/D: col = lane&31 = t -> coalesced 4B/lane stores.
__global__ __launch_bounds__(512, 4)
void subject_gemm(const float* __restrict__ x,
                  const int*   __restrict__ subjects,
                  const float* __restrict__ w,
                  float*       __restrict__ out)
{
    __shared__ __align__(16) unsigned char lds[2 * 32 * 512];   // 32 KiB total

    const int tid  = threadIdx.x;
    const int lane = tid & 63;
    const int wv   = tid >> 6;      // 0..7 : d-subtile
    const int g    = lane >> 5;     // k-group / c-half
    const int l31  = lane & 31;     // t within tile (and d within subtile for W)
    const int b    = blockIdx.y;
    const int t0   = blockIdx.x * CHUNK;

    const int sub = subjects[b];
    const float* __restrict__ wsub = w + (size_t)sub * NC * ND;
    const float* __restrict__ xb   = x + (size_t)b * NC * NT;
    float*       __restrict__ ob   = out + (size_t)b * ND * NT;

    const int dlane = wv * 32 + l31;

    // ---- one-time: W fragments (fp16) in registers; lane&31 = d, k(c) = 8g+j ----
    half8 wf[16];
#pragma unroll
    for (int ks = 0; ks < 16; ++ks) {
        float f[8];
#pragma unroll
        for (int j = 0; j < 8; ++j)
            f[j] = wsub[(size_t)(ks * 16 + g * 8 + j) * ND + dlane];
        FragA tmp;
#pragma unroll
        for (int p = 0; p < 4; ++p) tmp.u[p] = pk_f16(f[2 * p], f[2 * p + 1]);
        wf[ks] = tmp.v;
    }

    // ---- staging: thread owns c in [c0, c0+16), t = l31 ----
    const int c0 = wv * 32 + g * 16;
    const uint32_t swz      = ((uint32_t)(l31 & 15)) << 4;
    const uint32_t wr_byte0 = (uint32_t)l31 * 512 + (((uint32_t)c0 * 2 +  0) ^ swz);
    const uint32_t wr_byte1 = (uint32_t)l31 * 512 + (((uint32_t)c0 * 2 + 16) ^ swz);
    const uint32_t rd_row   = (uint32_t)l31 * 512;

    const float* xg = xb + (size_t)c0 * NT + t0 + l31;   // + i*NT + tile*BT

    float stage[16];

    // prologue: stage tile 0
#pragma unroll
    for (int i = 0; i < 16; ++i) stage[i] = xg[(size_t)i * NT];
    {
        uint4 q0, q1;
        q0.x = pk_f16(stage[0],  stage[1]);  q0.y = pk_f16(stage[2],  stage[3]);
        q0.z = pk_f16(stage[4],  stage[5]);  q0.w = pk_f16(stage[6],  stage[7]);
        q1.x = pk_f16(stage[8],  stage[9]);  q1.y = pk_f16(stage[10], stage[11]);
        q1.z = pk_f16(stage[12], stage[13]); q1.w = pk_f16(stage[14], stage[15]);
        *reinterpret_cast<uint4*>(&lds[wr_byte0]) = q0;
        *reinterpret_cast<uint4*>(&lds[wr_byte1]) = q1;
    }
    __syncthreads();

    for (int tile = 0; tile < NTILES; ++tile) {
        const uint32_t bufoff = (uint32_t)(tile & 1) * 16384;

        // issue next tile's 16 global loads first; pin them above compute
        if (tile + 1 < NTILES) {
            const float* src = xg + (size_t)(tile + 1) * BT;
#pragma unroll
            for (int i = 0; i < 16; ++i) stage[i] = src[(size_t)i * NT];
            __builtin_amdgcn_sched_barrier(0);
        }

        // ---- compute: 32(d) x 32(t) per wave, K=256 in 16 MFMA steps ----
        f32x16 acc = {};
#pragma unroll
        for (int ks = 0; ks < 16; ++ks) {
            const uint32_t colb = ((uint32_t)(ks * 32 + g * 16)) ^ swz;
            FragA a;
            a.q = *reinterpret_cast<const uint4*>(&lds[bufoff + rd_row + colb]);
            acc = __builtin_amdgcn_mfma_f32_32x32x16_f16(wf[ks], a.v, acc, 0, 0, 0);
        }

        // ---- store: col = lane&31 = t ; row d = (reg&3) + 8*(reg>>2) + 4*g ----
        const int tcol = t0 + tile * BT;
#pragma unroll
        for (int rg = 0; rg < 16; ++rg) {
            const int drow = wv * 32 + (rg & 3) + 8 * (rg >> 2) + 4 * g;
            ob[(size_t)drow * NT + tcol + l31] = acc[rg];
        }

        // convert + ds_write staged tile into the other buffer
        if (tile + 1 < NTILES) {
            const uint32_t nb = (uint32_t)((tile + 1) & 1) * 16384;
            uint4 q0, q1;
            q0.x = pk_f16(stage[0],  stage[1]);  q0.y = pk_f16(stage[2],  stage[3]);
            q0.z = pk_f16(stage[4],  stage[5]);  q0.w = pk_f16(stage[6],  stage[7]);
            q1.x = pk_f16(stage[8],  stage[9]);  q1.y = pk_f16(stage[10], stage[11]);
            q1.z = pk_f16(stage[12], stage[13]); q1.w = pk_f16(stage[14], stage[15]);
            *reinterpret_cast<uint4*>(&lds[nb + wr_byte0]) = q0;
            *reinterpret_cast<uint4*>(&lds[nb + wr_byte1]) = q1;
        }
        __syncthreads();
    }
}

extern "C" void kernel_launch(void* const* d_in, const int* in_sizes, int n_in,
                              void* d_out, int out_size, void* d_ws, size_t ws_size,
                              hipStream_t stream)
{
    const float* x        = (const float*)d_in[0];
    const int*   subjects = (const int*)d_in[1];
    const float* w        = (const float*)d_in[2];
    float*       out      = (float*)d_out;

    dim3 grid(NCHUNK, NB);   // 16 x 64 = 1024 blocks of 512 threads = 4 per CU
    subject_gemm<<<grid, 512, 0, stream>>>(x, subjects, w, out);
}

// Round 9
// 175.782 us; speedup vs baseline: 2.4981x; 2.4981x over previous
//
#include <hip/hip_runtime.h>
#include <cstdint>

#define NB 64
#define NC 256
#define ND 256
#define NT 4096

#define BT 32                    // t-columns per tile
#define NTILES 16                // tiles per block
#define CHUNK (BT * NTILES)      // 512 t per block
#define NCHUNK (NT / CHUNK)      // 8 chunks per b -> 512 blocks total = 2 per CU

typedef __attribute__((ext_vector_type(8)))  _Float16 half8;
typedef __attribute__((ext_vector_type(16))) float    f32x16;

union FragA { uint32_t u[4]; uint4 q; half8 v; };

__device__ __forceinline__ uint32_t pk_f16(float lo, float hi) {
    // v_cvt_pkrtz_f16_f32: D.lo=f16(lo), D.hi=f16(hi) — matches MFMA (k even, k odd) packing
    return __builtin_bit_cast(uint32_t, __builtin_amdgcn_cvt_pkrtz(lo, hi));
}

// Structure: EXACT R7 config (126 µs known-good): 512-thread blocks (8 waves),
// each wave owns d in [wv*32, wv*32+32), block covers full d for a 512-t chunk,
// 512 blocks = 2/CU, 32 KiB LDS, plain __syncthreads().
//
// NEW (only change): XCD-aware block swizzle over b. Dispatch round-robins
// linear block id over the 8 XCDs (id & 7 = XCD). Map:
//   xcd = id & 7, chunk = (id >> 3) & 7, b = xcd + 8 * (id >> 6)
// so each XCD hosts 8 fixed b's (all their chunks co-resident: 64 blocks =
// 32 CU x 2). W working set per XCD = <=8 subjects x 256 KB ~ 2 MB -> fits the
// 4 MB per-XCD L2, so the per-block W re-stream (256 KB x 512 blocks = 134 MB)
// hits L2 instead of LLC/HBM. (R8 lesson: W re-fetch + L2 thrash, not TLP,
// is the remaining cost — 1024 scattered blocks gave 747 MB FETCH, 3.5x dur.)
//
// LDS (per buffer, 16 KiB): fp16 x-tile [t=0..31][c=0..255], row = 512 B,
// byte(t,c) = t*512 + ((2c) ^ ((t&15)<<4))  — XOR swizzle, same on write & read.
//
// MFMA: D[m=d][n=t] = sum_c W^T[d][c] * X[c][t]
//   A = W frag (lane&31 = d, k = 8*(lane>>5)+j), B = x frag (lane&31 = t)
//   C/D: col = lane&31 = t -> coalesced 4B/lane stores.
__global__ __launch_bounds__(512, 4)
void subject_gemm(const float* __restrict__ x,
                  const int*   __restrict__ subjects,
                  const float* __restrict__ w,
                  float*       __restrict__ out)
{
    __shared__ __align__(16) unsigned char lds[2 * 32 * 512];   // 32 KiB total

    const int tid  = threadIdx.x;
    const int lane = tid & 63;
    const int wv   = tid >> 6;      // 0..7 : d-subtile
    const int g    = lane >> 5;     // k-group / c-half
    const int l31  = lane & 31;     // t within tile (and d within subtile for W)

    // ---- XCD-aware decode of (b, chunk) from 1-D block id ----
    const int id    = blockIdx.x;
    const int xcd   = id & 7;
    const int chunk = (id >> 3) & 7;
    const int b     = xcd + 8 * (id >> 6);
    const int t0    = chunk * CHUNK;

    const int sub = subjects[b];
    const float* __restrict__ wsub = w + (size_t)sub * NC * ND;
    const float* __restrict__ xb   = x + (size_t)b * NC * NT;
    float*       __restrict__ ob   = out + (size_t)b * ND * NT;

    const int dlane = wv * 32 + l31;

    // ---- one-time: W fragments (fp16) in registers; lane&31 = d, k(c) = 8g+j ----
    half8 wf[16];
#pragma unroll
    for (int ks = 0; ks < 16; ++ks) {
        float f[8];
#pragma unroll
        for (int j = 0; j < 8; ++j)
            f[j] = wsub[(size_t)(ks * 16 + g * 8 + j) * ND + dlane];
        FragA tmp;
#pragma unroll
        for (int p = 0; p < 4; ++p) tmp.u[p] = pk_f16(f[2 * p], f[2 * p + 1]);
        wf[ks] = tmp.v;
    }

    // ---- staging: thread owns c in [c0, c0+16), t = l31 ----
    const int c0 = wv * 32 + g * 16;
    const uint32_t swz      = ((uint32_t)(l31 & 15)) << 4;
    const uint32_t wr_byte0 = (uint32_t)l31 * 512 + (((uint32_t)c0 * 2 +  0) ^ swz);
    const uint32_t wr_byte1 = (uint32_t)l31 * 512 + (((uint32_t)c0 * 2 + 16) ^ swz);
    const uint32_t rd_row   = (uint32_t)l31 * 512;

    const float* xg = xb + (size_t)c0 * NT + t0 + l31;   // + i*NT + tile*BT

    float stage[16];

    // prologue: stage tile 0
#pragma unroll
    for (int i = 0; i < 16; ++i) stage[i] = xg[(size_t)i * NT];
    {
        uint4 q0, q1;
        q0.x = pk_f16(stage[0],  stage[1]);  q0.y = pk_f16(stage[2],  stage[3]);
        q0.z = pk_f16(stage[4],  stage[5]);  q0.w = pk_f16(stage[6],  stage[7]);
        q1.x = pk_f16(stage[8],  stage[9]);  q1.y = pk_f16(stage[10], stage[11]);
        q1.z = pk_f16(stage[12], stage[13]); q1.w = pk_f16(stage[14], stage[15]);
        *reinterpret_cast<uint4*>(&lds[wr_byte0]) = q0;
        *reinterpret_cast<uint4*>(&lds[wr_byte1]) = q1;
    }
    __syncthreads();

    for (int tile = 0; tile < NTILES; ++tile) {
        const uint32_t bufoff = (uint32_t)(tile & 1) * 16384;

        // issue next tile's 16 global loads first; pin them above compute
        if (tile + 1 < NTILES) {
            const float* src = xg + (size_t)(tile + 1) * BT;
#pragma unroll
            for (int i = 0; i < 16; ++i) stage[i] = src[(size_t)i * NT];
            __builtin_amdgcn_sched_barrier(0);
        }

        // ---- compute: 32(d) x 32(t) per wave, K=256 in 16 MFMA steps ----
        f32x16 acc = {};
#pragma unroll
        for (int ks = 0; ks < 16; ++ks) {
            const uint32_t colb = ((uint32_t)(ks * 32 + g * 16)) ^ swz;
            FragA a;
            a.q = *reinterpret_cast<const uint4*>(&lds[bufoff + rd_row + colb]);
            acc = __builtin_amdgcn_mfma_f32_32x32x16_f16(wf[ks], a.v, acc, 0, 0, 0);
        }

        // ---- store: col = lane&31 = t ; row d = (reg&3) + 8*(reg>>2) + 4*g ----
        const int tcol = t0 + tile * BT;
#pragma unroll
        for (int rg = 0; rg < 16; ++rg) {
            const int drow = wv * 32 + (rg & 3) + 8 * (rg >> 2) + 4 * g;
            ob[(size_t)drow * NT + tcol + l31] = acc[rg];
        }

        // convert + ds_write staged tile into the other buffer
        if (tile + 1 < NTILES) {
            const uint32_t nb = (uint32_t)((tile + 1) & 1) * 16384;
            uint4 q0, q1;
            q0.x = pk_f16(stage[0],  stage[1]);  q0.y = pk_f16(stage[2],  stage[3]);
            q0.z = pk_f16(stage[4],  stage[5]);  q0.w = pk_f16(stage[6],  stage[7]);
            q1.x = pk_f16(stage[8],  stage[9]);  q1.y = pk_f16(stage[10], stage[11]);
            q1.z = pk_f16(stage[12], stage[13]); q1.w = pk_f16(stage[14], stage[15]);
            *reinterpret_cast<uint4*>(&lds[nb + wr_byte0]) = q0;
            *reinterpret_cast<uint4*>(&lds[nb + wr_byte1]) = q1;
        }
        __syncthreads();
    }
}

extern "C" void kernel_launch(void* const* d_in, const int* in_sizes, int n_in,
                              void* d_out, int out_size, void* d_ws, size_t ws_size,
                              hipStream_t stream)
{
    const float* x        = (const float*)d_in[0];
    const int*   subjects = (const int*)d_in[1];
    const float* w        = (const float*)d_in[2];
    float*       out      = (float*)d_out;

    subject_gemm<<<dim3(NB * NCHUNK), 512, 0, stream>>>(x, subjects, w, out);
}